// Round 2
// baseline (579.675 us; speedup 1.0000x reference)
//
#include <hip/hip_runtime.h>

#define Hdim 128
#define Tlen 512
#define BT 8      // batch rows per block -> grid 256 = 1 block/CU
#define STR 136   // padded LDS row stride in fp16 elems (272B = 17x16B)

typedef __attribute__((ext_vector_type(8))) _Float16 f16x8;
typedef __attribute__((ext_vector_type(4))) float f32x4;

__device__ __forceinline__ f32x4 mfma_f16(f16x8 a, f16x8 b, f32x4 c) {
  return __builtin_amdgcn_mfma_f32_16x16x32_f16(a, b, c, 0, 0, 0);
}

// R12: staggered two-group software pipeline (bit-exact cell math vs R8/R10).
// R11 post-mortem: setprio was neutral because the per-step barrier re-locks
// wave phases — both waves/SIMD always in the same {MFMA|trans} phase, pipes
// serialize (VALUBusy 54.6 + MfmaUtil 34.8 ~ additive, ~600 cyc/step stalls).
// Fix is structural: batches are independent recurrences. Split 8 rows into
// groups A(0-3)/B(4-7), stagger by half a step. Each phase = [gate-extract Y
// (covers bfX LDS latency) ; MFMA X ; trans pointwise Y + h-write ; barrier ;
// reload bfY]. Every MFMA gets a full phase of independent VALU before its
// acc is consumed; every ds_read a phase before its MFMA. MFMA issue doubles
// (n=4 useful cols) to ~320 cyc/SIMD/step — hidden under ~900-cyc VALU floor.
// Cell arithmetic is instruction-identical (same MFMA k-order, same pointwise
// sequence, fp16 RNE h) -> trajectory bit-identical, absmax must = 0.0078125.
// Lane owns 1 cell/group: batch=l16&3, unit=16w+quad*4+(l16>>2) via 3-cndmask
// reg routing (replaces dpp_shl8). W pre-scaled -log2e (i,f,o) / +2log2e (g).
__global__ __launch_bounds__(512, 2)
void lstm_disc_kernel(const float* __restrict__ x, const float* __restrict__ hx0,
                      const float* __restrict__ cx0, const float* __restrict__ W_ih,
                      const float* __restrict__ W_hh, const float* __restrict__ b_ih,
                      const float* __restrict__ b_hh, const float* __restrict__ W_mlp,
                      const float* __restrict__ b_mlp, float* __restrict__ out) {
  __shared__ _Float16 hbuf0[BT * STR];
  __shared__ _Float16 hbuf1[BT * STR];

  const int tid  = threadIdx.x;
  const int w    = tid >> 6;          // wave 0..7
  const int lane = tid & 63;
  const int l16  = lane & 15;         // B col n / A row m
  const int quad = lane >> 4;         // 0..3
  const int b0   = blockIdx.x * BT;
  const int bg   = l16 & 3;           // batch row within group (cols dup x4)
  const int uu   = quad * 4 + (l16 >> 2);  // unit within wave-tile (0..15)
  const int ua   = 16 * w + uu;            // absolute unit (0..127)
  const bool j1  = (l16 & 4) != 0;    // reg-select bit 0
  const bool j2  = (l16 & 8) != 0;    // reg-select bit 1

  // ---- A fragments: W_hh pre-scaled; shared by both groups ----
  f16x8 wh[4][4];
  float wihG[4], biasG[4];
#pragma unroll
  for (int s = 0; s < 4; s++) {
    const float sc = (s == 2) ? 2.88539008f : -1.44269504f;  // g : i,f,o
    const int j = 16 * w + 128 * s + l16;       // gate row, type s
#pragma unroll
    for (int q = 0; q < 4; q++) {
      const float* p = W_hh + j * Hdim + q * 32 + quad * 8;
      f16x8 f;
#pragma unroll
      for (int e = 0; e < 8; e++) f[e] = (_Float16)(p[e] * sc);
      wh[s][q] = f;
    }
    const int jr = 16 * w + 128 * s + uu;       // owned gate row
    wihG[s]  = W_ih[jr] * sc;
    biasG[s] = (b_ih[jr] + b_hh[jr]) * sc;
  }

  // ---- h0 -> hbuf0 rows 0-7, fp16 RNE ----
  for (int i = tid; i < BT * Hdim; i += 512) {
    const int b = i >> 7, k = i & 127;
    hbuf0[b * STR + k] = (_Float16)hx0[(b0 + b) * Hdim + k];
  }

  // ---- c0: lane owns cell (unit ua, batch bg) per group ----
  float cA = cx0[(b0 + bg) * Hdim + ua];
  float cB = cx0[(b0 + 4 + bg) * Hdim + ua];

  const float* xpA = x + (b0 + bg) * Tlen;
  const float* xpB = x + (b0 + 4 + bg) * Tlen;
  float xA0 = xpA[0], xA1 = xpA[1], xB0 = xpB[0], xB1 = xpB[1];

  __syncthreads();

  const f32x4 Z = {0.0f, 0.0f, 0.0f, 0.0f};
  f16x8 bfA[4], bfB[4];
  f32x4 accA[4], accB[4];

  // ---- prologue: read both frags from h0; prime MFMA_A(0) ----
#pragma unroll
  for (int q = 0; q < 4; q++) {
    bfA[q] = *(const f16x8*)&hbuf0[bg * STR + q * 32 + quad * 8];
    bfB[q] = *(const f16x8*)&hbuf0[(4 + bg) * STR + q * 32 + quad * 8];
  }
#pragma unroll
  for (int s = 0; s < 4; s++) accA[s] = mfma_f16(wh[s][0], bfA[0], Z);
#pragma unroll
  for (int q = 1; q < 4; q++)
#pragma unroll
    for (int s = 0; s < 4; s++) accA[s] = mfma_f16(wh[s][q], bfA[q], accA[s]);
  __syncthreads();   // protect hbuf0 from phase-0 writes until all reads done

  // phase(X = MFMA group, Y = pointwise group):
  //   1. extract gates Y from accY (indep of bfX -> covers its LDS latency)
  //   2. issue 16 MFMAs for X into accX (consumed next phase)
  //   3. trans pointwise Y, write h_Y to bufY
  //   4. barrier; reload bfY from bufY (consumed next phase)
  auto phase = [&](f32x4 (&accX)[4], f16x8 (&bfX)[4],
                   f32x4 (&accY)[4], f16x8 (&bfY)[4],
                   float& cY, float xY, _Float16* __restrict__ bufY) {
    float G[4];
#pragma unroll
    for (int s = 0; s < 4; s++) {
      float t0 = j1 ? accY[s][1] : accY[s][0];
      float t1 = j1 ? accY[s][3] : accY[s][2];
      float g  = j2 ? t1 : t0;
      G[s] = __builtin_fmaf(xY, wihG[s], g + biasG[s]);
    }

#pragma unroll
    for (int s = 0; s < 4; s++) accX[s] = mfma_f16(wh[s][0], bfX[0], Z);
#pragma unroll
    for (int q = 1; q < 4; q++)
#pragma unroll
      for (int s = 0; s < 4; s++) accX[s] = mfma_f16(wh[s][q], bfX[q], accX[s]);

    // LSTM pointwise, 1 cell, gates pre-scaled (identical op sequence to R8)
    float iv = __builtin_amdgcn_rcpf(1.0f + __builtin_amdgcn_exp2f(G[0]));
    float fv = __builtin_amdgcn_rcpf(1.0f + __builtin_amdgcn_exp2f(G[1]));
    float gv = 1.0f - 2.0f * __builtin_amdgcn_rcpf(
                            __builtin_amdgcn_exp2f(G[2]) + 1.0f);
    float ov = __builtin_amdgcn_rcpf(1.0f + __builtin_amdgcn_exp2f(G[3]));
    float cn = __builtin_fmaf(fv, cY, iv * gv);
    cY = cn;
    float tc = 1.0f - 2.0f * __builtin_amdgcn_rcpf(
                            __builtin_amdgcn_exp2f(cn * 2.88539008f) + 1.0f);
    float hv = ov * tc;
    bufY[bg * STR + ua] = (_Float16)hv;   // RNE, ds_write_b16

    __syncthreads();
#pragma unroll
    for (int q = 0; q < 4; q++)
      bfY[q] = *(const f16x8*)&bufY[bg * STR + q * 32 + quad * 8];
  };

  for (int t = 0; t < Tlen; t += 2) {
    const int tn = t + 2;
    float nA0 = xpA[(tn     < Tlen) ? tn     : Tlen - 1];
    float nA1 = xpA[(tn + 1 < Tlen) ? tn + 1 : Tlen - 1];
    float nB0 = xpB[(tn     < Tlen) ? tn     : Tlen - 1];
    float nB1 = xpB[(tn + 1 < Tlen) ? tn + 1 : Tlen - 1];
    phase(accB, bfB, accA, bfA, cA, xA0, hbuf0);            // alpha(t)
    phase(accA, bfA, accB, bfB, cB, xB0, hbuf0 + 4 * STR);  // beta(t)
    phase(accB, bfB, accA, bfA, cA, xA1, hbuf1);            // alpha(t+1)
    phase(accA, bfA, accB, bfB, cB, xB1, hbuf1 + 4 * STR);  // beta(t+1)
    xA0 = nA0; xA1 = nA1; xB0 = nB0; xB1 = nB1;
  }

  // ---- epilogue: final h (step 511, parity 1) lives in hbuf1 rows 0-7 ----
  if (tid < BT) {
    float s = 0.0f;
#pragma unroll 8
    for (int k = 0; k < Hdim; k++)
      s += (float)hbuf1[tid * STR + k] * W_mlp[k];
    out[b0 + tid] = __builtin_amdgcn_rcpf(
        1.0f + __builtin_amdgcn_exp2f((s + b_mlp[0]) * -1.44269504f));
  }
}

extern "C" void kernel_launch(void* const* d_in, const int* in_sizes, int n_in,
                              void* d_out, int out_size, void* d_ws, size_t ws_size,
                              hipStream_t stream) {
  const float* x     = (const float*)d_in[0];
  const float* hx0   = (const float*)d_in[1];
  const float* cx0   = (const float*)d_in[2];
  const float* W_ih  = (const float*)d_in[3];
  const float* W_hh  = (const float*)d_in[4];
  const float* b_ih  = (const float*)d_in[5];
  const float* b_hh  = (const float*)d_in[6];
  const float* W_mlp = (const float*)d_in[7];
  const float* b_mlp = (const float*)d_in[8];
  float* out = (float*)d_out;

  const int B = in_sizes[1] / Hdim;   // hx0 is [B, H]
  dim3 grid(B / BT), block(512);
  lstm_disc_kernel<<<grid, block, 0, stream>>>(x, hx0, cx0, W_ih, W_hh, b_ih,
                                               b_hh, W_mlp, b_mlp, out);
}

// Round 3
// 346.737 us; speedup vs baseline: 1.6718x; 1.6718x over previous
//
#include <hip/hip_runtime.h>

#define Hdim 128
#define Tlen 512
#define BT 8      // batch rows per block -> grid 256 = 1 block/CU
#define STR 136   // padded LDS row stride in fp16 elems (272B = 17x16B)

typedef __attribute__((ext_vector_type(8))) _Float16 f16x8;
typedef __attribute__((ext_vector_type(2))) _Float16 f16x2;
typedef __attribute__((ext_vector_type(4))) float f32x4;

__device__ __forceinline__ f32x4 mfma_f16(f16x8 a, f16x8 b, f32x4 c) {
  return __builtin_amdgcn_mfma_f32_16x16x32_f16(a, b, c, 0, 0, 0);
}
// dest lane i (within 16-lane DPP row): i>=8 gets src lane i-8's v; i<8 keeps
// `old` (bound_ctrl=false). Rebalances C-regs 2,3 onto the duplicate lanes.
__device__ __forceinline__ float dpp_shl8(float old, float v) {
  int r = __builtin_amdgcn_update_dpp(__builtin_bit_cast(int, old),
                                      __builtin_bit_cast(int, v),
                                      0x108 /*row_shl:8*/, 0xF, 0xF, false);
  return __builtin_bit_cast(float, r);
}

// R13 = R10 structure + common-denominator pointwise (7 trans/cell, was 10).
// HW model (locked in by R12's counters: phase = (300 MFMA + 380 VALU) x 2
// waves = 1360 cyc measured): the SIMD issue port SERIALIZES all waves'
// instruction streams; v_mfma 16x16x32 occupies issue ~18.4 cyc (per-SIMD
// rate; 4.85-cyc ubench figure is per-CU). No MFMA/VALU overlap is possible
// on a SIMD -> setprio (R11 null) and stagger (R12 +60%) are dead ends; only
// total issue-cycle reduction helps. R10 budget/SIMD/step: MFMA 590 (fixed:
// 128 MFMAs/CU from 8 batches/CU dup x2, best shape) + VALU ~924 (trans-
// dominated: 20 trans/wave @ ~16 cyc) + stall ~180 = 1693 cyc.
// This round: merge rcps via common denominators (gate path G[] unchanged):
//   cn = [c*(1+A)(1+B) + (B-1)(1+F)] * rcp((1+A)(1+B)(1+F))
//      = sigmoid(f)*c + sigmoid(i)*tanh(g)        (A=e^-i, B=e^2g, F=e^-f)
//   hv = (D-1) * rcp((1+O)(1+D)) = sigmoid(o)*tanh(cn)   (D=e^2cn, O=e^-o)
// 5 exp2 + 2 rcp per cell (was 5+5). Overflow needs |i|+2|g|+|f| > ~89 nats
// -> unreachable. Numerics: trajectory rerolls (chaotic); R12's reroll gave
// absmax 0.00195 vs budget ~0.0098 — coin flip, revert if fail.
// Structure: 8 waves, BT=8, wave w owns M-tiles {w+8s} = gates i,f,g,o of
// units 16w..16w+15; B cols 8-15 duplicate 0-7; h fp16 RNE; c fp32-resident;
// one barrier/step; W pre-scaled -log2e (i,f,o) / +2log2e (g).
__global__ __launch_bounds__(512, 2)
void lstm_disc_kernel(const float* __restrict__ x, const float* __restrict__ hx0,
                      const float* __restrict__ cx0, const float* __restrict__ W_ih,
                      const float* __restrict__ W_hh, const float* __restrict__ b_ih,
                      const float* __restrict__ b_hh, const float* __restrict__ W_mlp,
                      const float* __restrict__ b_mlp, float* __restrict__ out) {
  __shared__ _Float16 hbuf0[BT * STR];
  __shared__ _Float16 hbuf1[BT * STR];

  const int tid  = threadIdx.x;
  const int w    = tid >> 6;          // wave 0..7
  const int lane = tid & 63;
  const int l16  = lane & 15;         // B col n / A row m
  const int quad = lane >> 4;         // 0..3
  const int b0   = blockIdx.x * BT;
  const int bb   = l16 & 7;           // batch row (cols 8-15 duplicate 0-7)
  const bool hi  = (l16 < 8);
  const int uoff = quad * 4 + (hi ? 0 : 2);   // in-wave unit offset (even)
  const int ub   = 16 * w + uoff;             // first owned unit

  // ---- A fragments: W_hh pre-scaled; x/bias terms in final cell layout ----
  f16x8 wh[4][4];
  float wihG[4][2], biasG[4][2];
#pragma unroll
  for (int s = 0; s < 4; s++) {
    const float sc = (s == 2) ? 2.88539008f : -1.44269504f;  // g : i,f,o
    const int j = 16 * w + 128 * s + l16;       // gate row, type s
#pragma unroll
    for (int q = 0; q < 4; q++) {
      const float* p = W_hh + j * Hdim + q * 32 + quad * 8;
      f16x8 f;
#pragma unroll
      for (int e = 0; e < 8; e++) f[e] = (_Float16)(p[e] * sc);
      wh[s][q] = f;
    }
#pragma unroll
    for (int r2 = 0; r2 < 2; r2++) {
      const int j2 = 16 * w + 128 * s + uoff + r2;
      wihG[s][r2]  = W_ih[j2] * sc;
      biasG[s][r2] = (b_ih[j2] + b_hh[j2]) * sc;
    }
  }

  // ---- h0 -> LDS rows 0-7, fp16 RNE ----
  for (int i = tid; i < BT * Hdim; i += 512) {
    const int b = i >> 7, k = i & 127;
    hbuf0[b * STR + k] = (_Float16)hx0[(b0 + b) * Hdim + k];
  }

  // ---- c0: lane owns units ub, ub+1 of batch bb ----
  float c[2] = {cx0[(b0 + bb) * Hdim + ub], cx0[(b0 + bb) * Hdim + ub + 1]};

  const float* xp = x + (b0 + bb) * Tlen;
  float xv[4] = {xp[0], xp[1], xp[2], xp[3]};

  __syncthreads();

  const f32x4 Z = {0.0f, 0.0f, 0.0f, 0.0f};

  auto step = [&](const _Float16* __restrict__ src, _Float16* __restrict__ dst,
                  float xcur) {
    // B frags: B[k=quad*8+e][n=l16], col n = batch bb (8-15 broadcast-dup)
    f16x8 bfrag[4];
#pragma unroll
    for (int q = 0; q < 4; q++)
      bfrag[q] = *(const f16x8*)&src[bb * STR + q * 32 + quad * 8];

    // four independent 4-deep MFMA chains (gate types i,f,g,o)
    f32x4 a[4];
#pragma unroll
    for (int s = 0; s < 4; s++) a[s] = mfma_f16(wh[s][0], bfrag[0], Z);
#pragma unroll
    for (int q = 1; q < 4; q++)
#pragma unroll
      for (int s = 0; s < 4; s++) a[s] = mfma_f16(wh[s][q], bfrag[q], a[s]);

    // rebalance: lanes >=8 take regs 2,3 from lane-8; add bias + x*W_ih
    float G[4][2];
#pragma unroll
    for (int s = 0; s < 4; s++)
#pragma unroll
      for (int r2 = 0; r2 < 2; r2++) {
        float g = dpp_shl8(a[s][r2], a[s][2 + r2]);
        G[s][r2] = __builtin_fmaf(xcur, wihG[s][r2], g + biasG[s][r2]);
      }

    // LSTM pointwise, 2 cells/lane, common-denominator forms: 5 exp2 + 2 rcp
    float hv[2];
#pragma unroll
    for (int r2 = 0; r2 < 2; r2++) {
      float A  = __builtin_amdgcn_exp2f(G[0][r2]);   // e^{-i}
      float F  = __builtin_amdgcn_exp2f(G[1][r2]);   // e^{-f}
      float Bv = __builtin_amdgcn_exp2f(G[2][r2]);   // e^{2g}
      float O  = __builtin_amdgcn_exp2f(G[3][r2]);   // e^{-o}
      float a1 = 1.0f + A, b1 = 1.0f + Bv, f1 = 1.0f + F;
      float t1 = a1 * b1;
      float num = __builtin_fmaf(c[r2], t1, (Bv - 1.0f) * f1);
      float cn  = num * __builtin_amdgcn_rcpf(t1 * f1);
      c[r2] = cn;
      float D  = __builtin_amdgcn_exp2f(cn * 2.88539008f);  // e^{2*cn}
      hv[r2] = (D - 1.0f) *
               __builtin_amdgcn_rcpf((1.0f + O) * (1.0f + D));
    }
    f16x2 hp;
    hp[0] = (_Float16)hv[0];   // RNE
    hp[1] = (_Float16)hv[1];
    *(f16x2*)&dst[bb * STR + ub] = hp;

    __syncthreads();
  };

  for (int t = 0; t < Tlen; t += 4) {
    const int tn = t + 4;
    float xa = xp[(tn     < Tlen) ? tn     : Tlen - 1];
    float xb = xp[(tn + 1 < Tlen) ? tn + 1 : Tlen - 1];
    float xc = xp[(tn + 2 < Tlen) ? tn + 2 : Tlen - 1];
    float xd = xp[(tn + 3 < Tlen) ? tn + 3 : Tlen - 1];
    step(hbuf0, hbuf1, xv[0]);
    step(hbuf1, hbuf0, xv[1]);
    step(hbuf0, hbuf1, xv[2]);
    step(hbuf1, hbuf0, xv[3]);
    xv[0] = xa; xv[1] = xb; xv[2] = xc; xv[3] = xd;
  }

  // ---- epilogue: out[b] = sigmoid(h . W_mlp + b_mlp); final h in hbuf0 ----
  if (tid < BT) {
    float s = 0.0f;
#pragma unroll 8
    for (int k = 0; k < Hdim; k++)
      s += (float)hbuf0[tid * STR + k] * W_mlp[k];
    out[b0 + tid] = __builtin_amdgcn_rcpf(
        1.0f + __builtin_amdgcn_exp2f((s + b_mlp[0]) * -1.44269504f));
  }
}

extern "C" void kernel_launch(void* const* d_in, const int* in_sizes, int n_in,
                              void* d_out, int out_size, void* d_ws, size_t ws_size,
                              hipStream_t stream) {
  const float* x     = (const float*)d_in[0];
  const float* hx0   = (const float*)d_in[1];
  const float* cx0   = (const float*)d_in[2];
  const float* W_ih  = (const float*)d_in[3];
  const float* W_hh  = (const float*)d_in[4];
  const float* b_ih  = (const float*)d_in[5];
  const float* b_hh  = (const float*)d_in[6];
  const float* W_mlp = (const float*)d_in[7];
  const float* b_mlp = (const float*)d_in[8];
  float* out = (float*)d_out;

  const int B = in_sizes[1] / Hdim;   // hx0 is [B, H]
  dim3 grid(B / BT), block(512);
  lstm_disc_kernel<<<grid, block, 0, stream>>>(x, hx0, cx0, W_ih, W_hh, b_ih,
                                               b_hh, W_mlp, b_mlp, out);
}